// Round 3
// baseline (353.211 us; speedup 1.0000x reference)
//
#include <hip/hip_runtime.h>

// cyclicLoss: out = mean((input-target)^2) + 0.1*sqrt( sum_{i<(N-1)*T} (input[i]-input[i+T])^2 )
// fp32, n = N*T = 2048*8192 = 16.8M elements (64 MB each array).
//
// R2 design: flat layout (R0's, which beat R1's column-walk), latency attack:
//   - U=4 items/thread at grid-stride offsets; all 12 dwordx4 loads issued
//     back-to-back, branch-free (shifted address clamped via cndmask) ->
//     ~12 outstanding loads/wave at ~28 waves/CU.
//   - grid 4096*256*4 == n4 exactly -> fast path only.
//   - fused last-block finalize (single dispatch + 4B memset).

#define LAMDA 0.1
#define BLOCK 256
#define U 4

__global__ __launch_bounds__(BLOCK) void cyclic_fused_kernel(
    const float4* __restrict__ in4,
    const float4* __restrict__ tg4,
    const int* __restrict__ pT,
    const int* __restrict__ pN,
    long long n,
    double* __restrict__ m_part,
    double* __restrict__ d_part,
    unsigned int* __restrict__ counter,
    float* __restrict__ out)
{
    const int T = pT[0];
    const int N = pN[0];
    const long long n4 = n >> 2;
    const long long t4 = (long long)T >> 2;
    const long long limit = (long long)(N - 1) * (long long)T;  // scalar diff bound
    const long long limit4 = limit >> 2;                        // full float4 groups

    float mse_acc = 0.0f;
    float dif_acc = 0.0f;

    const long long nth  = (long long)gridDim.x * BLOCK;
    const long long gtid = (long long)blockIdx.x * BLOCK + threadIdx.x;

    long long base = gtid;

    // ---- fast path: U batched, branch-free iterations ----
    for (; base + (long long)(U - 1) * nth < n4; base += (long long)U * nth) {
        long long idx[U];
        float4 a[U], b[U], c[U];
        #pragma unroll
        for (int u = 0; u < U; ++u) idx[u] = base + (long long)u * nth;
        #pragma unroll
        for (int u = 0; u < U; ++u) a[u] = in4[idx[u]];
        #pragma unroll
        for (int u = 0; u < U; ++u) b[u] = tg4[idx[u]];
        #pragma unroll
        for (int u = 0; u < U; ++u) {
            // clamp: always a legal address, no branch between loads
            long long j = (idx[u] < limit4) ? (idx[u] + t4) : idx[u];
            c[u] = in4[j];
        }
        #pragma unroll
        for (int u = 0; u < U; ++u) {
            float e0 = a[u].x - b[u].x, e1 = a[u].y - b[u].y;
            float e2 = a[u].z - b[u].z, e3 = a[u].w - b[u].w;
            mse_acc += e0 * e0 + e1 * e1 + e2 * e2 + e3 * e3;
            float d0 = a[u].x - c[u].x, d1 = a[u].y - c[u].y;
            float d2 = a[u].z - c[u].z, d3 = a[u].w - c[u].w;
            float dd = d0 * d0 + d1 * d1 + d2 * d2 + d3 * d3;
            dif_acc += (idx[u] < limit4) ? dd : 0.0f;   // cndmask, no branch
        }
    }

    // ---- remainder float4s (none for the bench shape; kept generic) ----
    for (; base < n4; base += nth) {
        float4 a = in4[base];
        float4 b = tg4[base];
        float e0 = a.x - b.x, e1 = a.y - b.y, e2 = a.z - b.z, e3 = a.w - b.w;
        mse_acc += e0 * e0 + e1 * e1 + e2 * e2 + e3 * e3;
        if (base < limit4) {
            float4 c = in4[base + t4];
            float d0 = a.x - c.x, d1 = a.y - c.y, d2 = a.z - c.z, d3 = a.w - c.w;
            dif_acc += d0 * d0 + d1 * d1 + d2 * d2 + d3 * d3;
        }
    }

    // ---- scalar tails (n % 4 and diff-boundary % 4; none here, kept generic) ----
    {
        const float* in = (const float*)in4;
        const float* tg = (const float*)tg4;
        long long idx = (n4 << 2) + gtid;
        if (idx < n) {
            float e = in[idx] - tg[idx];
            mse_acc += e * e;
        }
        long long didx = (limit4 << 2) + gtid;
        if (didx < limit) {
            float d = in[didx] - in[didx + T];
            dif_acc += d * d;
        }
    }

    // ---- block reduction: wave-64 shuffle, then LDS across 4 waves ----
    #pragma unroll
    for (int off = 32; off > 0; off >>= 1) {
        mse_acc += __shfl_down(mse_acc, off, 64);
        dif_acc += __shfl_down(dif_acc, off, 64);
    }
    __shared__ float s_m[4], s_d[4];
    const int wave = threadIdx.x >> 6;
    if ((threadIdx.x & 63) == 0) { s_m[wave] = mse_acc; s_d[wave] = dif_acc; }
    __syncthreads();

    __shared__ bool isLast;
    if (threadIdx.x == 0) {
        double m = (double)s_m[0] + (double)s_m[1] + (double)s_m[2] + (double)s_m[3];
        double d = (double)s_d[0] + (double)s_d[1] + (double)s_d[2] + (double)s_d[3];
        m_part[blockIdx.x] = m;
        d_part[blockIdx.x] = d;
        __threadfence();
        unsigned int old = atomicAdd(counter, 1u);
        isLast = (old == gridDim.x - 1);
    }
    __syncthreads();

    // ---- last block finalizes ----
    if (isLast) {
        __threadfence();
        double m = 0.0, d = 0.0;
        for (int i = threadIdx.x; i < (int)gridDim.x; i += BLOCK) {
            m += m_part[i];
            d += d_part[i];
        }
        #pragma unroll
        for (int off = 32; off > 0; off >>= 1) {
            m += __shfl_down(m, off, 64);
            d += __shfl_down(d, off, 64);
        }
        __shared__ double f_m[4], f_d[4];
        if ((threadIdx.x & 63) == 0) { f_m[wave] = m; f_d[wave] = d; }
        __syncthreads();
        if (threadIdx.x == 0) {
            double mt = f_m[0] + f_m[1] + f_m[2] + f_m[3];
            double dt = f_d[0] + f_d[1] + f_d[2] + f_d[3];
            double mse = mt / (double)n;
            double nom = (N != 1) ? (LAMDA * sqrt(dt)) : 0.0;
            out[0] = (float)(mse + nom);
        }
    }
}

extern "C" void kernel_launch(void* const* d_in, const int* in_sizes, int n_in,
                              void* d_out, int out_size, void* d_ws, size_t ws_size,
                              hipStream_t stream) {
    const float* input  = (const float*)d_in[0];
    const float* target = (const float*)d_in[1];
    const int*   pT     = (const int*)d_in[2];
    const int*   pN     = (const int*)d_in[3];
    float* out = (float*)d_out;

    const long long n = (long long)in_sizes[0];

    const int grid = 4096;   // 4096*256*U == 4,194,304 == n/4 exactly
    double* m_part = (double*)d_ws;
    double* d_part = m_part + grid;
    unsigned int* counter = (unsigned int*)(d_part + grid);

    hipMemsetAsync(counter, 0, sizeof(unsigned int), stream);

    cyclic_fused_kernel<<<grid, BLOCK, 0, stream>>>(
        (const float4*)input, (const float4*)target, pT, pN, n,
        m_part, d_part, counter, out);
}